// Round 4
// baseline (945.595 us; speedup 1.0000x reference)
//
#include <hip/hip_runtime.h>
#include <hip/hip_bf16.h>
#include <math.h>

// SplineConv GNN: out = descs + 0.1 * conv2(relu(conv1(descs)))
// Round 3 -> 4: GEMM upgraded from m97 2-barrier structure (792 TF measured) to a
// counted-vmcnt pipelined structure: 256x128 tile, BK=64, 8 waves, TRIPLE-buffered
// LDS staging 2 K-tiles ahead, raw s_barrier + s_waitcnt vmcnt(6) (never 0 in loop),
// XOR-16B LDS swizzle (pre-swizzled global source + swizzled ds_read), setprio
// around MFMA, bijective XCD grid swizzle. Everything else unchanged from round 3.

#define DN 4096
#define DE 65536
#define DF 1024
#define NMAT 26
#define NCOLS (NMAT * DF)   // 26624

typedef __attribute__((ext_vector_type(8))) short short8;
typedef __attribute__((ext_vector_type(4))) float f32x4;
typedef unsigned long long ull;

__device__ __forceinline__ float bf2f(unsigned short u) {
    return __uint_as_float(((unsigned int)u) << 16);
}
__device__ __forceinline__ unsigned short f2bf(float f) {
    unsigned int x = __float_as_uint(f);
    x += 0x7fffu + ((x >> 16) & 1u);   // RTNE (no NaN inputs in this pipeline)
    return (unsigned short)(x >> 16);
}
__device__ __forceinline__ void gld16(const unsigned short* g, unsigned short* l) {
    __builtin_amdgcn_global_load_lds(
        (const __attribute__((address_space(1))) unsigned int*)g,
        (__attribute__((address_space(3))) unsigned int*)l, 16, 0, 0);
}

// ---------------- fp32 -> bf16 convert (x input) ----------------
__global__ void k_convert_x(const float* __restrict__ x, unsigned short* __restrict__ xb) {
    int i = (blockIdx.x * blockDim.x + threadIdx.x) * 4;
    float4 v = *(const float4*)(x + i);
    union { unsigned short u[4]; ull ll; } o;
    o.u[0] = f2bf(v.x); o.u[1] = f2bf(v.y); o.u[2] = f2bf(v.z); o.u[3] = f2bf(v.w);
    *(ull*)(xb + i) = o.ll;
}

// ---------------- CSR build over heads ----------------
__global__ void k_hist(const int* __restrict__ heads, int* __restrict__ cnt) {
    int e = blockIdx.x * blockDim.x + threadIdx.x;
    atomicAdd(&cnt[heads[e]], 1);
}

__global__ __launch_bounds__(1024)
void k_scan(const int* __restrict__ cnt, int* __restrict__ row_off, int* __restrict__ cursor) {
    __shared__ int part[1024];
    int tid = threadIdx.x;
    int base = tid * 4;
    int v[4], s = 0;
#pragma unroll
    for (int j = 0; j < 4; ++j) { v[j] = s; s += cnt[base + j]; }
    part[tid] = s;
    __syncthreads();
    for (int off = 1; off < 1024; off <<= 1) {
        int t = (tid >= off) ? part[tid - off] : 0;
        __syncthreads();
        part[tid] += t;
        __syncthreads();
    }
    int excl = (tid == 0) ? 0 : part[tid - 1];
#pragma unroll
    for (int j = 0; j < 4; ++j) {
        row_off[base + j] = excl + v[j];
        cursor[base + j]  = excl + v[j];
    }
    if (tid == 1023) row_off[4096] = part[1023];
}

__global__ void k_scatter(const float* __restrict__ pts,
                          const int* __restrict__ tails, const int* __restrict__ heads,
                          int* __restrict__ cursor,
                          int2* __restrict__ ei, float4* __restrict__ eb) {
    int e = blockIdx.x * blockDim.x + threadIdx.x;
    int t = tails[e], h = heads[e];
    float ptx = pts[2 * t], pty = pts[2 * t + 1];
    float phx = pts[2 * h], phy = pts[2 * h + 1];
    float p0 = fminf(fmaxf((ptx - phx) * (0.5f / 256.f) + 0.5f, 0.f), 1.f);
    float p1 = fminf(fmaxf((pty - phy) * (0.5f / 256.f) + 0.5f, 0.f), 1.f);
    float v0 = p0 * 4.f, v1 = p1 * 4.f;
    float f0 = fminf(floorf(v0), 3.f), f1 = fminf(floorf(v1), 3.f);
    float fr0 = v0 - f0, fr1 = v1 - f1;
    int i0 = (int)f0, i1 = (int)f1;
    int wi0 = i0 + i1 * 5;
    float4 b;
    b.x = (1.f - fr0) * (1.f - fr1);
    b.y = fr0 * (1.f - fr1);
    b.z = (1.f - fr0) * fr1;
    b.w = fr0 * fr1;
    int pos = atomicAdd(&cursor[h], 1);
    ei[pos] = make_int2(t, wi0 | ((wi0 + 1) << 8) | ((wi0 + 5) << 16) | ((wi0 + 6) << 24));
    eb[pos] = b;
}

// ---------------- W[k][i][o] fp32  ->  Wbt[k][o][i] bf16 ----------------
__global__ void k_transpose_w(const float* __restrict__ W, const float* __restrict__ root,
                              unsigned short* __restrict__ Wbt) {
    __shared__ float tile[64][65];
    int mat = blockIdx.z;
    const float* src = (mat < 25) ? (W + (size_t)mat * DF * DF) : root;
    unsigned short* dst = Wbt + (size_t)mat * DF * DF;
    int i0 = blockIdx.x * 64;
    int o0 = blockIdx.y * 64;
    int tx = threadIdx.x & 63, ty = threadIdx.x >> 6;
#pragma unroll
    for (int j = 0; j < 16; ++j) {
        int r = j * 4 + ty;
        tile[r][tx] = src[(size_t)(i0 + r) * DF + o0 + tx];
    }
    __syncthreads();
#pragma unroll
    for (int j = 0; j < 16; ++j) {
        int c = j * 4 + ty;
        dst[(size_t)(o0 + c) * DF + i0 + tx] = f2bf(tile[tx][c]);
    }
}

// ---------------- GEMM: C[4096, 26624] = A[4096,1024] @ B^T rows ----------------
// 256x128 tile, BK=64, 8 waves of 64x64, triple-buffered LDS, 2-tiles-ahead
// prefetch with counted vmcnt(6).  LDS swizzle: kbyte ^= ((row&7)<<4), applied
// to the global SOURCE address at stage time and to the ds_read address.
__global__ __launch_bounds__(512, 2)
void k_gemm(const unsigned short* __restrict__ A,
            const unsigned short* __restrict__ B,
            unsigned short* __restrict__ C)
{
    __shared__ unsigned short As[3][16384];   // 3 bufs x 256 rows x 64 (32 KB each)
    __shared__ unsigned short Bs[3][8192];    // 3 bufs x 128 rows x 64 (16 KB each)

    const int tid = threadIdx.x;
    const int w  = tid >> 6, ln = tid & 63;
    const int wr = w >> 1,  wc = w & 1;       // 4x2 wave grid, 64x64 per wave

    // bijective XCD swizzle: nwg = 16*208 = 3328, 3328/8 = 416
    int wg  = blockIdx.x;
    int swz = (wg & 7) * 416 + (wg >> 3);
    int bm  = swz / 208, bn = swz - bm * 208;

    const size_t abase = (size_t)bm * 256 * 1024;
    const size_t bbase = (size_t)bn * 128 * 1024;

    // staging lane constants: lane writes LDS bytes [base + ln*16); that slot's
    // logical (row, kbyte) gets global data from kbyte ^ ((row&7)<<4).
    const int lrow = ln >> 3;                     // row-within-wave-chunk (0..7)
    const int lswz = ((ln & 7) ^ lrow) * 8;       // swizzled k element offset

#define STAGE_A(l, kt, b) \
    gld16(A + abase + (size_t)((l) * 64 + w * 8 + lrow) * 1024 + (size_t)(kt) * 64 + lswz, \
          &As[b][(l) * 4096 + w * 512]);
#define STAGE_B(l, kt, b) \
    gld16(B + bbase + (size_t)((l) * 64 + w * 8 + lrow) * 1024 + (size_t)(kt) * 64 + lswz, \
          &Bs[b][(l) * 4096 + w * 512]);

    f32x4 acc[4][4];
#pragma unroll
    for (int m = 0; m < 4; ++m)
#pragma unroll
        for (int n = 0; n < 4; ++n) acc[m][n] = (f32x4){0.f, 0.f, 0.f, 0.f};

    // fragment read constants: slot = ((ks<<2)|klane) ^ (rsel&7), elem = slot*8
    const int rsel  = ln & 15, klane = ln >> 4;
    const int sl0   = ((klane ^ (rsel & 7)) * 8);   // ks=0
    const int sl1   = sl0 ^ 32;                     // ks=1 (slot^4 -> elem^32)
    int arow[4], brow[4];
#pragma unroll
    for (int m = 0; m < 4; ++m) arow[m] = (wr * 64 + m * 16 + rsel) * 64;
#pragma unroll
    for (int n = 0; n < 4; ++n) brow[n] = (wc * 64 + n * 16 + rsel) * 64;

    // ---- prologue: stage tiles 0 and 1 ----
    STAGE_A(0, 0, 0) STAGE_A(1, 0, 0) STAGE_A(2, 0, 0) STAGE_A(3, 0, 0)
    STAGE_B(0, 0, 0) STAGE_B(1, 0, 0)
    STAGE_A(0, 1, 1) STAGE_A(1, 1, 1) STAGE_A(2, 1, 1) STAGE_A(3, 1, 1)
    STAGE_B(0, 1, 1) STAGE_B(1, 1, 1)
    asm volatile("s_waitcnt vmcnt(6)" ::: "memory");   // tile 0 landed
    __builtin_amdgcn_s_barrier();

    int cb = 0;
#pragma unroll 1
    for (int t = 0; t < 16; ++t) {
        int sb = cb + 2; if (sb >= 3) sb -= 3;
        const unsigned short* Ab = &As[cb][0];
        const unsigned short* Bb = &Bs[cb][0];
        const bool st = (t + 2) < 16;

        // ---- phase 0: kslice 0 ----
        short8 af[4], bf[4];
#pragma unroll
        for (int m = 0; m < 4; ++m) af[m] = *(const short8*)&Ab[arow[m] + sl0];
#pragma unroll
        for (int n = 0; n < 4; ++n) bf[n] = *(const short8*)&Bb[brow[n] + sl0];
        if (st) { STAGE_A(0, t + 2, sb) STAGE_A(1, t + 2, sb) STAGE_A(2, t + 2, sb) }
        __builtin_amdgcn_s_barrier();
        __builtin_amdgcn_s_setprio(1);
#pragma unroll
        for (int m = 0; m < 4; ++m)
#pragma unroll
            for (int n = 0; n < 4; ++n)
                acc[m][n] = __builtin_amdgcn_mfma_f32_16x16x32_bf16(af[m], bf[n], acc[m][n], 0, 0, 0);
        __builtin_amdgcn_s_setprio(0);
        __builtin_amdgcn_s_barrier();

        // ---- phase 1: kslice 1 ----
#pragma unroll
        for (int m = 0; m < 4; ++m) af[m] = *(const short8*)&Ab[arow[m] + sl1];
#pragma unroll
        for (int n = 0; n < 4; ++n) bf[n] = *(const short8*)&Bb[brow[n] + sl1];
        if (st) { STAGE_A(3, t + 2, sb) STAGE_B(0, t + 2, sb) STAGE_B(1, t + 2, sb) }
        __builtin_amdgcn_s_barrier();
        __builtin_amdgcn_s_setprio(1);
#pragma unroll
        for (int m = 0; m < 4; ++m)
#pragma unroll
            for (int n = 0; n < 4; ++n)
                acc[m][n] = __builtin_amdgcn_mfma_f32_16x16x32_bf16(af[m], bf[n], acc[m][n], 0, 0, 0);
        __builtin_amdgcn_s_setprio(0);
        if (t < 14)       { asm volatile("s_waitcnt vmcnt(6)" ::: "memory"); }  // tile t+1 landed
        else if (t == 14) { asm volatile("s_waitcnt vmcnt(0)" ::: "memory"); }  // epilogue drain
        __builtin_amdgcn_s_barrier();
        cb = cb + 1; if (cb >= 3) cb = 0;
    }
#undef STAGE_A
#undef STAGE_B

    // epilogue: C/D layout col=lane&15, row=(lane>>4)*4+reg
    const int r0 = (ln >> 4) * 4;
#pragma unroll
    for (int m = 0; m < 4; ++m) {
#pragma unroll
        for (int n = 0; n < 4; ++n) {
            int row = bm * 256 + wr * 64 + m * 16 + r0;
            int col = bn * 128 + wc * 64 + n * 16 + (ln & 15);
#pragma unroll
            for (int r = 0; r < 4; ++r)
                C[(size_t)(row + r) * NCOLS + col] = f2bf(acc[m][n][r]);
        }
    }
}

// ---------------- segment max, one block per destination node; fused epilogue ----------------
template <int LAYER>
__global__ __launch_bounds__(256)
void k_agg(const int* __restrict__ row_off,
           const int2* __restrict__ ei, const float4* __restrict__ eb,
           const unsigned short* __restrict__ Z,
           const float* __restrict__ bias,
           const float* __restrict__ descs,
           unsigned short* __restrict__ h1b, float* __restrict__ out)
{
    __shared__ int2  sei[64];
    __shared__ float4 seb[64];
    const int n = blockIdx.x;
    const int tid = threadIdx.x;
    const int d = tid * 4;
    const int s0 = row_off[n], s1 = row_off[n + 1];

    float vm0 = -3.3e38f, vm1 = -3.3e38f, vm2 = -3.3e38f, vm3 = -3.3e38f;

    for (int chunk = s0; chunk < s1; chunk += 64) {
        int cnum = min(64, s1 - chunk);
        if (tid < cnum) { sei[tid] = ei[chunk + tid]; seb[tid] = eb[chunk + tid]; }
        __syncthreads();
        for (int j = 0; j < cnum; ++j) {
            int2 ep = sei[j];
            float4 b = seb[j];
            const unsigned short* zt = Z + (size_t)ep.x * NCOLS + d;
            int w = ep.y;
            ull q0 = *(const ull*)(zt + ((w      ) & 255) * DF);
            ull q1 = *(const ull*)(zt + ((w >> 8 ) & 255) * DF);
            ull q2 = *(const ull*)(zt + ((w >> 16) & 255) * DF);
            ull q3 = *(const ull*)(zt + ((w >> 24) & 255) * DF);
            float m0 = b.x * bf2f((unsigned short)q0) + b.y * bf2f((unsigned short)q1)
                     + b.z * bf2f((unsigned short)q2) + b.w * bf2f((unsigned short)q3);
            float m1 = b.x * bf2f((unsigned short)(q0 >> 16)) + b.y * bf2f((unsigned short)(q1 >> 16))
                     + b.z * bf2f((unsigned short)(q2 >> 16)) + b.w * bf2f((unsigned short)(q3 >> 16));
            float m2 = b.x * bf2f((unsigned short)(q0 >> 32)) + b.y * bf2f((unsigned short)(q1 >> 32))
                     + b.z * bf2f((unsigned short)(q2 >> 32)) + b.w * bf2f((unsigned short)(q3 >> 32));
            float m3 = b.x * bf2f((unsigned short)(q0 >> 48)) + b.y * bf2f((unsigned short)(q1 >> 48))
                     + b.z * bf2f((unsigned short)(q2 >> 48)) + b.w * bf2f((unsigned short)(q3 >> 48));
            vm0 = fmaxf(vm0, m0); vm1 = fmaxf(vm1, m1);
            vm2 = fmaxf(vm2, m2); vm3 = fmaxf(vm3, m3);
        }
        __syncthreads();
    }
    if (s1 == s0) { vm0 = vm1 = vm2 = vm3 = 0.f; }   // empty segment -> 0

    const unsigned short* zr = Z + (size_t)n * NCOLS + 25 * DF + d;
    ull qr = *(const ull*)zr;
    float z0 = bf2f((unsigned short)qr),         z1 = bf2f((unsigned short)(qr >> 16));
    float z2 = bf2f((unsigned short)(qr >> 32)), z3 = bf2f((unsigned short)(qr >> 48));
    float b0 = bias[d], b1 = bias[d + 1], b2 = bias[d + 2], b3 = bias[d + 3];
    size_t o = (size_t)n * DF + d;
    if (LAYER == 1) {
        union { unsigned short u[4]; ull ll; } ov;
        ov.u[0] = f2bf(fmaxf(vm0 + z0 + b0, 0.f));
        ov.u[1] = f2bf(fmaxf(vm1 + z1 + b1, 0.f));
        ov.u[2] = f2bf(fmaxf(vm2 + z2 + b2, 0.f));
        ov.u[3] = f2bf(fmaxf(vm3 + z3 + b3, 0.f));
        *(ull*)(h1b + o) = ov.ll;
    } else {
        float4 dv = *(const float4*)(descs + o);
        float4 r;
        r.x = dv.x + 0.1f * (vm0 + z0 + b0);
        r.y = dv.y + 0.1f * (vm1 + z1 + b1);
        r.z = dv.z + 0.1f * (vm2 + z2 + b2);
        r.w = dv.w + 0.1f * (vm3 + z3 + b3);
        *(float4*)(out + o) = r;
    }
}

extern "C" void kernel_launch(void* const* d_in, const int* in_sizes, int n_in,
                              void* d_out, int out_size, void* d_ws, size_t ws_size,
                              hipStream_t stream) {
    const float* descs = (const float*)d_in[0];
    const float* pts   = (const float*)d_in[1];
    const float* W1    = (const float*)d_in[2];
    const float* root1 = (const float*)d_in[3];
    const float* bias1 = (const float*)d_in[4];
    const float* W2    = (const float*)d_in[5];
    const float* root2 = (const float*)d_in[6];
    const float* bias2 = (const float*)d_in[7];
    const int* tails   = (const int*)d_in[8];
    const int* heads   = (const int*)d_in[9];
    float* out = (float*)d_out;

    char* ws = (char*)d_ws;
    unsigned short* Wbt = (unsigned short*)ws;  ws += (size_t)NMAT * DF * DF * 2;
    unsigned short* xb  = (unsigned short*)ws;  ws += (size_t)DN * DF * 2;
    unsigned short* h1b = (unsigned short*)ws;  ws += (size_t)DN * DF * 2;
    unsigned short* Z   = (unsigned short*)ws;  ws += (size_t)DN * NCOLS * 2;
    int*  cnt     = (int*)ws;   ws += DN * 4;
    int*  row_off = (int*)ws;   ws += (DN + 1) * 4 + 4;
    int*  cursor  = (int*)ws;   ws += DN * 4;
    int2* ei      = (int2*)ws;  ws += (size_t)DE * 8;
    float4* eb    = (float4*)ws; ws += (size_t)DE * 16;

    // ---- graph structure (shared by both layers) ----
    hipMemsetAsync(cnt, 0, DN * 4, stream);
    k_convert_x<<<DN * DF / 4 / 256, 256, 0, stream>>>(descs, xb);
    k_hist<<<DE / 256, 256, 0, stream>>>(heads, cnt);
    k_scan<<<1, 1024, 0, stream>>>(cnt, row_off, cursor);
    k_scatter<<<DE / 256, 256, 0, stream>>>(pts, tails, heads, cursor, ei, eb);

    // ---- layer 1 ----
    k_transpose_w<<<dim3(16, 16, NMAT), 256, 0, stream>>>(W1, root1, Wbt);
    k_gemm<<<(DN / 256) * (NCOLS / 128), 512, 0, stream>>>(xb, Wbt, Z);
    k_agg<1><<<DN, 256, 0, stream>>>(row_off, ei, eb, Z, bias1, nullptr, h1b, nullptr);

    // ---- layer 2 ----
    k_transpose_w<<<dim3(16, 16, NMAT), 256, 0, stream>>>(W2, root2, Wbt);
    k_gemm<<<(DN / 256) * (NCOLS / 128), 512, 0, stream>>>(h1b, Wbt, Z);
    k_agg<2><<<DN, 256, 0, stream>>>(row_off, ei, eb, Z, bias2, descs, nullptr, out);
}